// Round 2
// baseline (621.385 us; speedup 1.0000x reference)
//
#include <hip/hip_runtime.h>

#define NE 8          // routed experts
#define HD 1024       // hidden
#define MD 2048       // intermediate
#define NT 2048       // tokens (2*1024)
#define NSH 4096      // shared-expert row base (= NT * topk)

typedef __attribute__((ext_vector_type(8))) short s16x8;
typedef __attribute__((ext_vector_type(4))) float f32x4;
typedef __attribute__((ext_vector_type(8))) unsigned short u16x8;
typedef __attribute__((ext_vector_type(4))) unsigned short u16x4;

__device__ __forceinline__ unsigned short f2bf(float f) {
    union { float f; unsigned int i; } v; v.f = f;
    unsigned int u = v.i;
    return (unsigned short)((u + 0x7FFFu + ((u >> 16) & 1u)) >> 16);
}
__device__ __forceinline__ float bf2f(unsigned short u) {
    union { unsigned int i; float f; } v; v.i = ((unsigned int)u) << 16; return v.f;
}

// ---------------- K0: fp32 -> bf16 bulk convert ----------------
__global__ __launch_bounds__(256) void k_cvt(
    const float* __restrict__ s, unsigned short* __restrict__ d, int n)
{
    int i = (blockIdx.x * 256 + threadIdx.x) * 4;
    int stride = gridDim.x * 256 * 4;
    for (; i < n; i += stride) {
        float4 v = *(const float4*)(s + i);
        u16x4 o;
        o[0] = f2bf(v.x); o[1] = f2bf(v.y); o[2] = f2bf(v.z); o[3] = f2bf(v.w);
        *(u16x4*)(d + i) = o;
    }
}

// ---------------- K1: routing (one wave per token, fp32) ----------------
__global__ __launch_bounds__(256) void k_route(
    const float* __restrict__ x, const float* __restrict__ gw,
    const float* __restrict__ beta,
    int* __restrict__ cnt, int* __restrict__ list, int* __restrict__ slot,
    float* __restrict__ rprob)
{
    int wave = threadIdx.x >> 6, lane = threadIdx.x & 63;
    int t = blockIdx.x * 4 + wave;
    const float4* xp = (const float4*)(x + (size_t)t * HD) + lane * 4;
    float4 xv[4];
    #pragma unroll
    for (int j = 0; j < 4; j++) xv[j] = xp[j];

    float logit[NE];
    #pragma unroll
    for (int e = 0; e < NE; e++) {
        const float4* gp = (const float4*)(gw + e * HD) + lane * 4;
        float s = 0.f;
        #pragma unroll
        for (int j = 0; j < 4; j++) {
            float4 g = gp[j];
            s += xv[j].x * g.x + xv[j].y * g.y + xv[j].z * g.z + xv[j].w * g.w;
        }
        for (int off = 32; off > 0; off >>= 1) s += __shfl_xor(s, off);
        logit[e] = s;
    }
    if (lane == 0) {
        float v[NE];
        #pragma unroll
        for (int e = 0; e < NE; e++) v[e] = logit[e] + beta[e];
        int i1 = 0; float m1 = v[0];
        #pragma unroll
        for (int e = 1; e < NE; e++) if (v[e] > m1) { m1 = v[e]; i1 = e; }
        int i2 = -1; float m2 = -3.4e38f;
        #pragma unroll
        for (int e = 0; e < NE; e++) if (e != i1 && v[e] > m2) { m2 = v[e]; i2 = e; }
        if (i2 < 0) i2 = (i1 + 1) & 7;   // hardening: never negative-index
        float p1 = 1.f / (1.f + __expf(-logit[i1]));
        float p2 = 1.f / (1.f + __expf(-logit[i2]));
        int pos1 = atomicAdd(cnt + i1, 1);
        list[i1 * NT + pos1] = t; slot[t * 2 + 0] = (i1 << 16) | pos1; rprob[t * 2 + 0] = p1;
        int pos2 = atomicAdd(cnt + i2, 1);
        list[i2 * NT + pos2] = t; slot[t * 2 + 1] = (i2 << 16) | pos2; rprob[t * 2 + 1] = p2;
    }
}

// ---------------- K2: tiny scan for row bases ----------------
__global__ void k_scan(const int* __restrict__ cnt, int* __restrict__ base) {
    if (threadIdx.x == 0) {
        int run = 0;
        for (int e = 0; e < NE; e++) { base[e] = run; run += cnt[e]; }
        base[NE] = run; // == NSH
    }
}

// ---------------- K3: gathered gate+up GEMM (bf16), fused SiLU ----------------
__global__ __launch_bounds__(256) void k_gateup(
    const unsigned short* __restrict__ x,
    const unsigned short* __restrict__ wg_all, const unsigned short* __restrict__ wu_all,
    const unsigned short* __restrict__ swg, const unsigned short* __restrict__ swu,
    const int* __restrict__ cnt, const int* __restrict__ base, const int* __restrict__ list,
    unsigned short* __restrict__ h)
{
    int e = blockIdx.z;
    int i0 = blockIdx.y * 128;
    int n0 = blockIdx.x * 128;
    int cnte = (e < NE) ? cnt[e] : NT;
    if (i0 >= cnte) return;
    int rbase = (e < NE) ? base[e] : NSH;
    const unsigned short* wg = (e < NE) ? wg_all + (size_t)e * HD * MD : swg;
    const unsigned short* wu = (e < NE) ? wu_all + (size_t)e * HD * MD : swu;

    __shared__ short As[128 * 40];     // A tile [128][32], stride 40
    __shared__ short Bg[32 * 136];     // B tiles k-major [32][128], stride 136
    __shared__ short Bu[32 * 136];
    __shared__ int tok[128];

    int tid = threadIdx.x;
    if (tid < 128) {
        int gi = i0 + tid;
        tok[tid] = (e < NE) ? ((gi < cnte) ? list[e * NT + gi] : -1) : gi;
    }

    int lane = tid & 63, wave = tid >> 6;
    int wr = (wave >> 1) * 64, wc = (wave & 1) * 64;
    int m = lane & 15, q = lane >> 4;

    f32x4 accG[4][4], accU[4][4];
    #pragma unroll
    for (int a = 0; a < 4; a++)
        #pragma unroll
        for (int b = 0; b < 4; b++) { accG[a][b] = (f32x4)0.f; accU[a][b] = (f32x4)0.f; }

    for (int k0 = 0; k0 < HD; k0 += 32) {
        __syncthreads();
        #pragma unroll
        for (int i = 0; i < 2; i++) {
            int idx = tid + i * 256;
            int row = idx >> 2, kc = (idx & 3) * 8;
            int tk = tok[row];
            u16x8 v = 0;
            if (tk >= 0) v = *(const u16x8*)(x + (size_t)tk * HD + k0 + kc);
            *(u16x8*)(&As[row * 40 + kc]) = v;
        }
        #pragma unroll
        for (int i = 0; i < 2; i++) {
            int idx = tid + i * 256;
            int k = idx >> 4, nc = (idx & 15) * 8;
            size_t off = (size_t)(k0 + k) * MD + n0 + nc;
            *(u16x8*)(&Bg[k * 136 + nc]) = *(const u16x8*)(wg + off);
            *(u16x8*)(&Bu[k * 136 + nc]) = *(const u16x8*)(wu + off);
        }
        __syncthreads();

        s16x8 af[4];
        #pragma unroll
        for (int ti = 0; ti < 4; ti++)
            af[ti] = *(const s16x8*)(&As[(wr + ti * 16 + m) * 40 + q * 8]);
        #pragma unroll
        for (int tj = 0; tj < 4; tj++) {
            int nn = wc + tj * 16 + m;
            s16x8 bg, bu;
            #pragma unroll
            for (int j = 0; j < 8; j++) {
                bg[j] = Bg[(q * 8 + j) * 136 + nn];
                bu[j] = Bu[(q * 8 + j) * 136 + nn];
            }
            #pragma unroll
            for (int ti = 0; ti < 4; ti++) {
                accG[ti][tj] = __builtin_amdgcn_mfma_f32_16x16x32_bf16(af[ti], bg, accG[ti][tj], 0, 0, 0);
                accU[ti][tj] = __builtin_amdgcn_mfma_f32_16x16x32_bf16(af[ti], bu, accU[ti][tj], 0, 0, 0);
            }
        }
    }
    // epilogue: silu(g)*u -> h  (D layout: row = q*4+r, col = m)
    #pragma unroll
    for (int ti = 0; ti < 4; ti++)
        #pragma unroll
        for (int tj = 0; tj < 4; tj++)
            #pragma unroll
            for (int r = 0; r < 4; r++) {
                int gi = i0 + wr + ti * 16 + q * 4 + r;
                if (gi < cnte) {
                    int col = n0 + wc + tj * 16 + m;
                    float g = accG[ti][tj][r], u = accU[ti][tj][r];
                    float hv = (g / (1.f + __expf(-g))) * u;
                    h[(size_t)(rbase + gi) * MD + col] = f2bf(hv);
                }
            }
}

// ---------------- K4: down projection (bf16) ----------------
__global__ __launch_bounds__(256) void k_down(
    const unsigned short* __restrict__ wd_all, const unsigned short* __restrict__ swd,
    const int* __restrict__ cnt, const int* __restrict__ base,
    const unsigned short* __restrict__ h, unsigned short* __restrict__ eo)
{
    int e = blockIdx.z;
    int i0 = blockIdx.y * 128;
    int n0 = blockIdx.x * 128;
    int cnte = (e < NE) ? cnt[e] : NT;
    if (i0 >= cnte) return;
    int rbase = (e < NE) ? base[e] : NSH;
    const unsigned short* wd = (e < NE) ? wd_all + (size_t)e * MD * HD : swd;

    __shared__ short As[128 * 40];
    __shared__ short Bd[32 * 136];

    int tid = threadIdx.x;
    int lane = tid & 63, wave = tid >> 6;
    int wr = (wave >> 1) * 64, wc = (wave & 1) * 64;
    int m = lane & 15, q = lane >> 4;

    f32x4 acc[4][4];
    #pragma unroll
    for (int a = 0; a < 4; a++)
        #pragma unroll
        for (int b = 0; b < 4; b++) acc[a][b] = (f32x4)0.f;

    for (int k0 = 0; k0 < MD; k0 += 32) {
        __syncthreads();
        #pragma unroll
        for (int i = 0; i < 2; i++) {
            int idx = tid + i * 256;
            int row = idx >> 2, kc = (idx & 3) * 8;
            int gi = i0 + row;
            u16x8 v = 0;
            if (gi < cnte) v = *(const u16x8*)(h + (size_t)(rbase + gi) * MD + k0 + kc);
            *(u16x8*)(&As[row * 40 + kc]) = v;
        }
        #pragma unroll
        for (int i = 0; i < 2; i++) {
            int idx = tid + i * 256;
            int k = idx >> 4, nc = (idx & 15) * 8;
            *(u16x8*)(&Bd[k * 136 + nc]) = *(const u16x8*)(wd + (size_t)(k0 + k) * HD + n0 + nc);
        }
        __syncthreads();

        s16x8 af[4];
        #pragma unroll
        for (int ti = 0; ti < 4; ti++)
            af[ti] = *(const s16x8*)(&As[(wr + ti * 16 + m) * 40 + q * 8]);
        #pragma unroll
        for (int tj = 0; tj < 4; tj++) {
            int nn = wc + tj * 16 + m;
            s16x8 bd;
            #pragma unroll
            for (int j = 0; j < 8; j++) bd[j] = Bd[(q * 8 + j) * 136 + nn];
            #pragma unroll
            for (int ti = 0; ti < 4; ti++)
                acc[ti][tj] = __builtin_amdgcn_mfma_f32_16x16x32_bf16(af[ti], bd, acc[ti][tj], 0, 0, 0);
        }
    }
    #pragma unroll
    for (int ti = 0; ti < 4; ti++)
        #pragma unroll
        for (int tj = 0; tj < 4; tj++)
            #pragma unroll
            for (int r = 0; r < 4; r++) {
                int gi = i0 + wr + ti * 16 + q * 4 + r;
                if (gi < cnte) {
                    int col = n0 + wc + tj * 16 + m;
                    eo[(size_t)(rbase + gi) * HD + col] = f2bf(acc[ti][tj][r]);
                }
            }
}

// ---------------- K5: weighted combine -> fp32 out ----------------
__global__ __launch_bounds__(256) void k_combine(
    const unsigned short* __restrict__ eo, const int* __restrict__ slot,
    const float* __restrict__ rprob, const int* __restrict__ base,
    float* __restrict__ out)
{
    int t = blockIdx.x;
    int s0 = slot[t * 2], s1 = slot[t * 2 + 1];
    float p0 = rprob[t * 2], p1 = rprob[t * 2 + 1];
    int r0 = base[s0 >> 16] + (s0 & 0xFFFF);
    int r1 = base[s1 >> 16] + (s1 & 0xFFFF);
    int rs = NSH + t;
    int c = threadIdx.x * 4;
    u16x4 a = *(const u16x4*)(eo + (size_t)r0 * HD + c);
    u16x4 b = *(const u16x4*)(eo + (size_t)r1 * HD + c);
    u16x4 s = *(const u16x4*)(eo + (size_t)rs * HD + c);
    float4 res;
    res.x = p0 * bf2f(a[0]) + p1 * bf2f(b[0]) + bf2f(s[0]);
    res.y = p0 * bf2f(a[1]) + p1 * bf2f(b[1]) + bf2f(s[1]);
    res.z = p0 * bf2f(a[2]) + p1 * bf2f(b[2]) + bf2f(s[2]);
    res.w = p0 * bf2f(a[3]) + p1 * bf2f(b[3]) + bf2f(s[3]);
    *(float4*)(out + (size_t)t * HD + c) = res;
}

extern "C" void kernel_launch(void* const* d_in, const int* in_sizes, int n_in,
                              void* d_out, int out_size, void* d_ws, size_t ws_size,
                              hipStream_t stream)
{
    const float* x    = (const float*)d_in[0];   // [2048,1024]
    const float* gw   = (const float*)d_in[1];   // [8,1024]
    const float* beta = (const float*)d_in[2];   // [8]
    const float* wg   = (const float*)d_in[3];   // [8,1024,2048]
    const float* wu   = (const float*)d_in[4];
    const float* wd   = (const float*)d_in[5];   // [8,2048,1024]
    const float* swg  = (const float*)d_in[6];   // [1,1024,2048]
    const float* swu  = (const float*)d_in[7];
    const float* swd  = (const float*)d_in[8];   // [1,2048,1024]
    float* out = (float*)d_out;

    char* ws = (char*)d_ws;
    const size_t MB = (size_t)1 << 20;
    int*   cnt   = (int*)(ws + 0);
    int*   basep = (int*)(ws + 64);
    int*   list  = (int*)(ws + 1024);                    // int[8][2048]
    int*   slot  = (int*)(ws + 1024 + 65536);            // int[2048][2]
    float* rprob = (float*)(ws + 1024 + 65536 + 16384);  // float[2048][2]
    unsigned short* xb   = (unsigned short*)(ws + 1 * MB);     // 4MB
    unsigned short* wgb  = (unsigned short*)(ws + 8 * MB);     // 32MB
    unsigned short* wub  = (unsigned short*)(ws + 40 * MB);    // 32MB
    unsigned short* wdb  = (unsigned short*)(ws + 72 * MB);    // 32MB
    unsigned short* swgb = (unsigned short*)(ws + 104 * MB);   // 4MB
    unsigned short* swub = (unsigned short*)(ws + 108 * MB);   // 4MB
    unsigned short* swdb = (unsigned short*)(ws + 112 * MB);   // 4MB
    unsigned short* h    = (unsigned short*)(ws + 116 * MB);   // bf16[6144][2048] 24MB
    unsigned short* eo   = (unsigned short*)(ws + 140 * MB);   // bf16[6144][1024] 12MB

    hipMemsetAsync(ws, 0, 128, stream);  // zero expert counters

    const int NX = NT * HD;       // 2,097,152
    const int NW = NE * HD * MD;  // 16,777,216
    k_cvt<<<2048, 256, 0, stream>>>(x,   xb,   NX);
    k_cvt<<<2048, 256, 0, stream>>>(wg,  wgb,  NW);
    k_cvt<<<2048, 256, 0, stream>>>(wu,  wub,  NW);
    k_cvt<<<2048, 256, 0, stream>>>(wd,  wdb,  NW);
    k_cvt<<<2048, 256, 0, stream>>>(swg, swgb, NX);
    k_cvt<<<2048, 256, 0, stream>>>(swu, swub, NX);
    k_cvt<<<2048, 256, 0, stream>>>(swd, swdb, NX);

    k_route<<<NT / 4, 256, 0, stream>>>(x, gw, beta, cnt, list, slot, rprob);
    k_scan<<<1, 64, 0, stream>>>(cnt, basep);

    dim3 g3(MD / 128, NT / 128, NE + 1);  // (16,16,9)
    k_gateup<<<g3, 256, 0, stream>>>(xb, wgb, wub, swgb, swub, cnt, basep, list, h);

    dim3 g4(HD / 128, NT / 128, NE + 1);  // (8,16,9)
    k_down<<<g4, 256, 0, stream>>>(wdb, swdb, cnt, basep, h, eo);

    k_combine<<<NT, 256, 0, stream>>>(eo, slot, rprob, basep, out);
}